// Round 16
// baseline (389.312 us; speedup 1.0000x reference)
//
#include <hip/hip_runtime.h>

// TCN, last-timestep receptive-field cone. SINGLE kernel (384 blocks x 256
// thr), 7 phases = round-15's 7 verified kernels, mechanically ported
// (shared arrays -> smem pointers; blockIdx -> explicit bx/by). 6 full-grid
// flag barriers (threadfence + device-scope atomic counter + spin).
// Co-residency guaranteed: __launch_bounds__(256,2) + 74.75KB LDS -> 2
// blocks/CU capacity = 512 >= 384. FL counters zeroed by in-graph memset.
// Workspace layout and all math identical to round 15 (passed, absmax 0.0).
// t maps: L0 u=ti+kk (x t=1011+u); down u=tj (x t=1015+2u); L1 u=2tj+kk;
// L2 u=tk+kk; L3 u=kk; residual H0 u=4 (t=1023).

#define OUTD 36
#define NB 384
#define AGT __HIP_MEMORY_SCOPE_AGENT
#define F4(q) (*(const float4*)(q))

__device__ __forceinline__ float4 relu4(float4 v) {
  v.x = fmaxf(v.x, 0.f); v.y = fmaxf(v.y, 0.f);
  v.z = fmaxf(v.z, 0.f); v.w = fmaxf(v.w, 0.f);
  return v;
}
__device__ __forceinline__ float4 add4(float4 a, float4 b) {
  a.x += b.x; a.y += b.y; a.z += b.z; a.w += b.w;
  return a;
}
__device__ __forceinline__ float4 addc4(float4 a, float c) {
  a.x += c; a.y += c; a.z += c; a.w += c;
  return a;
}

// full-grid barrier: release stores -> arrive -> spin -> acquire
__device__ __forceinline__ void gbar(int* cnt) {
  __syncthreads();  // all waves' global stores drained (vmcnt0 @ s_barrier)
  if (threadIdx.x == 0) {
    __threadfence();  // release: write back this XCD's L2
    __hip_atomic_fetch_add(cnt, 1, __ATOMIC_ACQ_REL, AGT);
    while (__hip_atomic_load(cnt, __ATOMIC_RELAXED, AGT) < NB)
      __builtin_amdgcn_s_sleep(2);
    __threadfence();  // acquire: invalidate before reading others' data
  }
  __syncthreads();
}

// ---- generic split-K conv-GEMM body (r15 verbatim; smem as param) -------
template <int CIN, int TS_N, int TP, int TOUT, int S, int D, int OFF, int TAPS,
          int OCT, int CCH, int NCH, bool SRC_X, int TS_BASE, int TS_STEP>
__device__ __forceinline__ void conv_body(int bx, int by,
                                          const float* __restrict__ src,
                                          const float* __restrict__ w,
                                          float* __restrict__ Pout,
                                          float* smem) {
    const int tid = threadIdx.x, lane = tid & 63, wv = tid >> 6;
    const int oc0 = bx * OCT;
    constexpr int OCR = OCT / 4;
    float* Als = smem;                     // [CCH*TAPS*OCT]
    float* Bls = smem + CCH * TAPS * OCT;  // [CCH*64*TP]
    float acc[OCR][TOUT];
#pragma unroll
    for (int i = 0; i < OCR; ++i)
#pragma unroll
        for (int t = 0; t < TOUT; ++t) acc[i][t] = 0.f;

    for (int ch = 0; ch < NCH; ++ch) {
        const int c0 = (by * NCH + ch) * CCH;
        if (ch) __syncthreads();
        for (int idx = tid; idx < OCT * CCH * TAPS; idx += 256) {
            int i = idx / (CCH * TAPS), r = idx % (CCH * TAPS);
            int c = r / TAPS, kk = r % TAPS;
            Als[(c * TAPS + kk) * OCT + i] =
                w[(size_t)(oc0 + i) * (CIN * TAPS) + (c0 + c) * TAPS + kk];
        }
        if constexpr (SRC_X) {
            for (int idx = tid; idx < CCH * TS_N * 64; idx += 256) {
                int c = idx % CCH, rb = idx / CCH;
                int b = rb & 63, u = rb >> 6;
                Bls[(c * 64 + b) * TP + u] =
                    src[((size_t)b * 1024 + 1011 + TS_BASE + TS_STEP * u) * 256 +
                        c0 + c];
            }
        } else {
            const float4* gp = (const float4*)(src + (size_t)c0 * 64 * TP);
            float4* lp = (float4*)Bls;
            for (int idx = tid; idx < CCH * 64 * TP / 4; idx += 256)
                lp[idx] = gp[idx];
        }
        __syncthreads();
        constexpr int NLOAD = (TP % 4 == 0) ? TP : TS_N;
        for (int c = 0; c < CCH; ++c) {
            float bv[NLOAD];
            if constexpr (TP % 4 == 0) {
#pragma unroll
                for (int q = 0; q < TP / 4; ++q)
                    *(float4*)&bv[4 * q] =
                        *(const float4*)&Bls[(c * 64 + lane) * TP + 4 * q];
            } else {
#pragma unroll
                for (int u = 0; u < TS_N; ++u)
                    bv[u] = Bls[(c * 64 + lane) * TP + u];
            }
            float av[TAPS][OCR];
#pragma unroll
            for (int kk = 0; kk < TAPS; ++kk)
#pragma unroll
                for (int j = 0; j < OCR; j += 4)
                    *(float4*)&av[kk][j] =
                        *(const float4*)&Als[(c * TAPS + kk) * OCT + wv * OCR + j];
#pragma unroll
            for (int i = 0; i < OCR; ++i)
#pragma unroll
                for (int t = 0; t < TOUT; ++t)
#pragma unroll
                    for (int kk = 0; kk < TAPS; ++kk)
                        acc[i][t] += av[kk][i] * bv[S * t + D * kk + OFF];
        }
    }
#pragma unroll
    for (int i = 0; i < OCR; ++i)
#pragma unroll
        for (int t = 0; t < TOUT; ++t)
            Pout[(((size_t)by * 512 + oc0 + wv * OCR + i) * TOUT + t) * 64 +
                 lane] = acc[i][t];
}

// ---- red0 body (r15 verbatim; Sm as param) ------------------------------
__device__ __forceinline__ void red0_body(int oc, const float* __restrict__ P0,
                                          const float* __restrict__ b1_0,
                                          float* __restrict__ B1, float* Sm) {
    const int tid = threadIdx.x;
    __syncthreads();  // guard LDS reuse across invocations/phases
    for (int i = tid; i < 768; i += 256) Sm[i] = 0.f;
    __syncthreads();
    if (tid < 176) {
        const int t = tid / 16, b4 = (tid % 16) * 4;
        float4 s = make_float4(0.f, 0.f, 0.f, 0.f);
#pragma unroll
        for (int p = 0; p < 8; ++p)
            s = add4(s, F4(P0 + (((size_t)p * 512 + oc) * 11 + t) * 64 + b4));
        s = relu4(addc4(s, b1_0[oc]));
        Sm[(b4 + 0) * 12 + t] = s.x;
        Sm[(b4 + 1) * 12 + t] = s.y;
        Sm[(b4 + 2) * 12 + t] = s.z;
        Sm[(b4 + 3) * 12 + t] = s.w;
    }
    __syncthreads();
    float4* op = (float4*)(B1 + (size_t)oc * 768);
    for (int i = tid; i < 192; i += 256) op[i] = *(const float4*)&Sm[4 * i];
}

// ---- red1 body (r15 verbatim; Sm as param; emits H0f) -------------------
__device__ __forceinline__ void red1_body(int oc, const float* __restrict__ P1,
                                          const float* __restrict__ b2_0,
                                          const float* __restrict__ PD,
                                          const float* __restrict__ bd0,
                                          float* __restrict__ H0,
                                          float* __restrict__ H0f, float* Sm) {
    const int tid = threadIdx.x;
    __syncthreads();
    for (int i = tid; i < 768; i += 256) Sm[i] = 0.f;
    __syncthreads();
    if (tid < 80) {
        const int t = tid / 16, b4 = (tid % 16) * 4;
        float4 s = make_float4(0.f, 0.f, 0.f, 0.f);
#pragma unroll
        for (int p = 0; p < 16; ++p)
            s = add4(s, F4(P1 + (((size_t)p * 512 + oc) * 5 + t) * 64 + b4));
        s = relu4(addc4(s, b2_0[oc]));
        float4 s2 = make_float4(0.f, 0.f, 0.f, 0.f);
#pragma unroll
        for (int p = 0; p < 8; ++p)
            s2 = add4(s2, F4(PD + (((size_t)p * 512 + oc) * 5 + t) * 64 + b4));
        s = relu4(addc4(add4(s, s2), bd0[oc]));
        Sm[(b4 + 0) * 12 + t] = s.x;
        Sm[(b4 + 1) * 12 + t] = s.y;
        Sm[(b4 + 2) * 12 + t] = s.z;
        Sm[(b4 + 3) * 12 + t] = s.w;
        if (t == 4) *(float4*)&H0f[(size_t)oc * 64 + b4] = s;
    }
    __syncthreads();
    float4* op = (float4*)(H0 + (size_t)oc * 768);
    for (int i = tid; i < 192; i += 256) op[i] = *(const float4*)&Sm[4 * i];
}

// ---- kD body (r15 verbatim; smem as param) ------------------------------
__device__ __forceinline__ void kD_body(int bid, const float* __restrict__ P2,
                                        const float* __restrict__ b1_1,
                                        const float* __restrict__ w2_1,
                                        float* __restrict__ P3, float* smem) {
  const int tid = threadIdx.x, lane = tid & 63, wv = tid >> 6;
  const int ocp = bid >> 3, ks = bid & 7, oc0 = ocp * 32;
  const int c0 = ks * 64;
  float* Als = smem;         // [64c][3kk][32oc] = 6144
  float* Bls = smem + 6144;  // [(c*3+u)*64+b]   = 12288
  float acc[8];
#pragma unroll
  for (int i = 0; i < 8; ++i) acc[i] = 0.f;
  for (int idx = tid; idx < 6144; idx += 256) {
    int i = idx / 192, r = idx % 192, c = r / 3, kk = r % 3;
    Als[(c * 3 + kk) * 32 + i] = w2_1[(oc0 + i) * 1536 + (c0 + c) * 3 + kk];
  }
  for (int idx = tid; idx < 3072; idx += 256) {
    int c = idx / 48, r = idx % 48, u = r / 16, b4 = (r & 15) * 4;
    int cc = c0 + c;
    float4 s = {0.f, 0.f, 0.f, 0.f};
#pragma unroll
    for (int p = 0; p < 8; ++p)
      s = add4(s, F4(&P2[((p * 512 + cc) * 3 + u) * 64 + b4]));
    *(float4*)&Bls[(c * 3 + u) * 64 + b4] = relu4(addc4(s, b1_1[cc]));
  }
  __syncthreads();
  for (int c = 0; c < 64; ++c) {
    float bv[3];
#pragma unroll
    for (int u = 0; u < 3; ++u) bv[u] = Bls[(c * 3 + u) * 64 + lane];
    float av[3][8];
#pragma unroll
    for (int kk = 0; kk < 3; ++kk) {
      *(float4*)&av[kk][0] = F4(&Als[(c * 3 + kk) * 32 + wv * 8]);
      *(float4*)&av[kk][4] = F4(&Als[(c * 3 + kk) * 32 + wv * 8 + 4]);
    }
#pragma unroll
    for (int i = 0; i < 8; ++i)
#pragma unroll
      for (int kk = 0; kk < 3; ++kk) acc[i] += av[kk][i] * bv[kk];
  }
#pragma unroll
  for (int i = 0; i < 8; ++i)
    P3[(ks * 512 + oc0 + wv * 8 + i) * 64 + lane] = acc[i];
}

// ---- kE body (r15 verbatim; smem as param) ------------------------------
__device__ __forceinline__ void kE_body(int j, const float* __restrict__ P3,
                                        const float* __restrict__ b2_1,
                                        const float* __restrict__ H0f,
                                        const float* __restrict__ fcw,
                                        const float* __restrict__ fcb,
                                        float* __restrict__ out, float* smem) {
  const int tid = threadIdx.x, lane = tid & 63, wv = tid >> 6;
  float* H1s = smem;          // [256 oc_l][64 b] per half = 16384
  float* red = smem + 16384;  // [4][64]
  float partial = (wv == 0) ? fcb[j] : 0.f;
  for (int half = 0; half < 2; ++half) {
    const int ocbase = half * 256;
    if (half) __syncthreads();
    for (int idx = tid; idx < 4096; idx += 256) {
      int oc_l = idx >> 4, b4 = (idx & 15) * 4;
      int oc = ocbase + oc_l;
      float4 s = {0.f, 0.f, 0.f, 0.f};
#pragma unroll
      for (int p = 0; p < 8; ++p)
        s = add4(s, F4(&P3[(p * 512 + oc) * 64 + b4]));
      s = relu4(addc4(s, b2_1[oc]));
      s = relu4(add4(s, F4(&H0f[(size_t)oc * 64 + b4])));
      *(float4*)&H1s[oc_l * 64 + b4] = s;
    }
    __syncthreads();
#pragma unroll 8
    for (int r = 0; r < 64; ++r) {
      int oc_l = wv * 64 + r;
      partial += fcw[j * 512 + ocbase + oc_l] * H1s[oc_l * 64 + lane];
    }
  }
  red[wv * 64 + lane] = partial;
  __syncthreads();
  if (wv == 0)
    out[lane * OUTD + j] = red[0 * 64 + lane] + red[1 * 64 + lane] +
                           red[2 * 64 + lane] + red[3 * 64 + lane];
}

struct Params {
  const float* x;
  const float *w1_0, *b1_0, *w2_0, *b2_0, *wd0, *bd0;
  const float *w1_1, *b1_1, *w2_1, *b2_1, *fcw, *fcb;
  float* out;
  float *P0, *B1, *P1, *PD, *H0, *P2, *P3, *H0f;
  int* FL;
};

__global__ __launch_bounds__(256, 2) void mega(Params p) {
  __shared__ float smem[18688];  // 74.75 KB (max phase: kD 18432; kE 16640)
  const int bid = blockIdx.x;

  // Phase 1: L0 conv (bid 0..255) + down conv (bid 256..383)
  if (bid < 256) {
    conv_body<256, 13, 13, 11, 1, 1, 0, 3, 16, 16, 2, true, 0, 1>(
        bid >> 3, bid & 7, p.x, p.w1_0, p.P0, smem);
  } else {
    const int q = bid - 256;
    conv_body<256, 5, 5, 5, 1, 0, 0, 1, 32, 16, 2, true, 4, 2>(
        q >> 3, q & 7, p.x, p.wd0, p.PD, smem);
  }
  gbar(&p.FL[0]);

  // Phase 2: red0 — B1 = relu(sum8 P0 + b1_0); oc = bid, bid+384
  red0_body(bid, p.P0, p.b1_0, p.B1, smem);
  if (bid < 128) red0_body(bid + 384, p.P0, p.b1_0, p.B1, smem);
  gbar(&p.FL[1]);

  // Phase 3: convL1 — B1 -> P1 (16 ocp x 16 ks; bid 0..255)
  if (bid < 256)
    conv_body<512, 11, 12, 5, 2, 1, 0, 3, 32, 16, 2, false, 0, 0>(
        bid & 15, bid >> 4, p.B1, p.w2_0, p.P1, smem);
  gbar(&p.FL[2]);

  // Phase 4: red1 — H0 (+H0f) = relu(relu(sum16 P1+b2_0)+sum8 PD+bd0)
  red1_body(bid, p.P1, p.b2_0, p.PD, p.bd0, p.H0, p.H0f, smem);
  if (bid < 128)
    red1_body(bid + 384, p.P1, p.b2_0, p.PD, p.bd0, p.H0, p.H0f, smem);
  gbar(&p.FL[3]);

  // Phase 5: convL2 — H0 -> P2 (16 ocp x 8 ks; bid 0..127)
  if (bid < 128)
    conv_body<512, 5, 12, 3, 1, 1, 0, 3, 32, 16, 4, false, 0, 0>(
        bid & 15, bid >> 4, p.H0, p.w1_1, p.P2, smem);
  gbar(&p.FL[4]);

  // Phase 6: kD — stage B2=relu(sum8 P2+b1_1); L3 conv -> P3 (bid 0..127)
  if (bid < 128) kD_body(bid, p.P2, p.b1_1, p.w2_1, p.P3, smem);
  gbar(&p.FL[5]);

  // Phase 7: kE — fc with fused sum8 P3 + residual (bid 0..35)
  if (bid < 36)
    kE_body(bid, p.P3, p.b2_1, p.H0f, p.fcw, p.fcb, p.out, smem);
}

extern "C" void kernel_launch(void* const* d_in, const int* in_sizes, int n_in,
                              void* d_out, int out_size, void* d_ws, size_t ws_size,
                              hipStream_t stream) {
  Params p;
  p.x    = (const float*)d_in[0];
  p.w1_0 = (const float*)d_in[4];
  p.b1_0 = (const float*)d_in[5];
  p.w2_0 = (const float*)d_in[6];
  p.b2_0 = (const float*)d_in[7];
  p.wd0  = (const float*)d_in[8];
  p.bd0  = (const float*)d_in[9];
  p.w1_1 = (const float*)d_in[10];
  p.b1_1 = (const float*)d_in[11];
  p.w2_1 = (const float*)d_in[12];
  p.b2_1 = (const float*)d_in[13];
  p.fcw  = (const float*)d_in[14];
  p.fcb  = (const float*)d_in[15];
  p.out  = (float*)d_out;

  float* base = (float*)d_ws;    // layout identical to round 15
  p.P0  = base;                  // 8*512*11*64 = 2,883,584
  p.B1  = p.P0 + 2883584;        // 512*64*12   =   393,216
  p.P1  = p.B1 + 393216;         // 16*512*5*64 = 2,621,440
  p.PD  = p.P1 + 2621440;        // 8*512*5*64  = 1,310,720
  p.H0  = p.PD + 1310720;        // 512*64*12   =   393,216
  p.P2  = p.H0 + 393216;         // 8*512*3*64  =   786,432
  p.P3  = p.P2 + 786432;         // 8*512*64    =   262,144
  p.H0f = p.P3 + 262144;         // 512*64      =    32,768
  p.FL  = (int*)(p.H0f + 32768); // 6 ints

  hipMemsetAsync((void*)p.FL, 0, 6 * sizeof(int), stream);
  mega<<<NB, 256, 0, stream>>>(p);
}

// Round 17
// 183.732 us; speedup vs baseline: 2.1189x; 2.1189x over previous
//
#include <hip/hip_runtime.h>

// TCN, last-timestep cone. SINGLE kernel, 256 blocks x 256 thr, 7 phases
// (round-15/16 verified bodies). Cross-block workspace data moves via
// agent-scope RELAXED atomics (sc1, coherent at Infinity Cache) so the
// grid barrier needs NO threadfence (r16's ~50us/barrier L2-flush cost).
// Barrier = syncthreads (vmcnt drain) -> relaxed atomicAdd -> relaxed spin.
// 256 blocks, 74.75KB LDS -> 1 block/CU guaranteed co-resident.
// Weights/x/out use plain cached loads/stores (read-only inputs / final).
// t maps: L0 u=ti+kk (x t=1011+u); down u=tj (x t=1015+2u); L1 u=2tj+kk;
// L2 u=tk+kk; L3 u=kk; residual H0 u=4 (t=1023).

#define OUTD 36
#define NB 256
#define AGT __HIP_MEMORY_SCOPE_AGENT
#define F4(q) (*(const float4*)(q))

// ---- coherent (IF-level) workspace ops ----------------------------------
__device__ __forceinline__ void stc(float* p, float v) {
  __hip_atomic_store((unsigned*)p, __float_as_uint(v), __ATOMIC_RELAXED, AGT);
}
__device__ __forceinline__ void stc2(float* p, float a, float b) {
  unsigned long long v = (unsigned long long)__float_as_uint(a) |
                         ((unsigned long long)__float_as_uint(b) << 32);
  __hip_atomic_store((unsigned long long*)p, v, __ATOMIC_RELAXED, AGT);
}
__device__ __forceinline__ float2 ldc2(const float* p) {
  unsigned long long v =
      __hip_atomic_load((const unsigned long long*)p, __ATOMIC_RELAXED, AGT);
  return make_float2(__uint_as_float((unsigned)v),
                     __uint_as_float((unsigned)(v >> 32)));
}
__device__ __forceinline__ float4 ldc4(const float* p) {
  float2 a = ldc2(p), b = ldc2(p + 2);
  return make_float4(a.x, a.y, b.x, b.y);
}
__device__ __forceinline__ void stc4(float* p, float4 v) {
  stc2(p, v.x, v.y);
  stc2(p + 2, v.z, v.w);
}
__device__ __forceinline__ float4 relu4(float4 v) {
  v.x = fmaxf(v.x, 0.f); v.y = fmaxf(v.y, 0.f);
  v.z = fmaxf(v.z, 0.f); v.w = fmaxf(v.w, 0.f);
  return v;
}
__device__ __forceinline__ float4 add4(float4 a, float4 b) {
  a.x += b.x; a.y += b.y; a.z += b.z; a.w += b.w;
  return a;
}
__device__ __forceinline__ float4 addc4(float4 a, float c) {
  a.x += c; a.y += c; a.z += c; a.w += c;
  return a;
}

// fence-free full-grid barrier (data coherence carried by sc1 ops)
__device__ __forceinline__ void gbar(int* cnt) {
  __syncthreads();  // all waves drain vmcnt before s_barrier -> stores done
  if (threadIdx.x == 0) {
    __hip_atomic_fetch_add(cnt, 1, __ATOMIC_RELAXED, AGT);
    while (__hip_atomic_load(cnt, __ATOMIC_RELAXED, AGT) < NB)
      __builtin_amdgcn_s_sleep(4);
  }
  __syncthreads();
}

// ---- generic split-K conv-GEMM body (r16 verbatim + sc1 workspace IO) ---
template <int CIN, int TS_N, int TP, int TOUT, int S, int D, int OFF, int TAPS,
          int OCT, int CCH, int NCH, bool SRC_X, int TS_BASE, int TS_STEP>
__device__ __forceinline__ void conv_body(int bx, int by,
                                          const float* __restrict__ src,
                                          const float* __restrict__ w,
                                          float* __restrict__ Pout,
                                          float* smem) {
    const int tid = threadIdx.x, lane = tid & 63, wv = tid >> 6;
    const int oc0 = bx * OCT;
    constexpr int OCR = OCT / 4;
    float* Als = smem;
    float* Bls = smem + CCH * TAPS * OCT;
    float acc[OCR][TOUT];
#pragma unroll
    for (int i = 0; i < OCR; ++i)
#pragma unroll
        for (int t = 0; t < TOUT; ++t) acc[i][t] = 0.f;

    for (int ch = 0; ch < NCH; ++ch) {
        const int c0 = (by * NCH + ch) * CCH;
        if (ch) __syncthreads();
        for (int idx = tid; idx < OCT * CCH * TAPS; idx += 256) {
            int i = idx / (CCH * TAPS), r = idx % (CCH * TAPS);
            int c = r / TAPS, kk = r % TAPS;
            Als[(c * TAPS + kk) * OCT + i] =
                w[(size_t)(oc0 + i) * (CIN * TAPS) + (c0 + c) * TAPS + kk];
        }
        if constexpr (SRC_X) {
            for (int idx = tid; idx < CCH * TS_N * 64; idx += 256) {
                int c = idx % CCH, rb = idx / CCH;
                int b = rb & 63, u = rb >> 6;
                Bls[(c * 64 + b) * TP + u] =
                    src[((size_t)b * 1024 + 1011 + TS_BASE + TS_STEP * u) * 256 +
                        c0 + c];
            }
        } else {
            const float* gp = src + (size_t)c0 * 64 * TP;
            float4* lp = (float4*)Bls;
            for (int idx = tid; idx < CCH * 64 * TP / 4; idx += 256)
                lp[idx] = ldc4(gp + idx * 4);
        }
        __syncthreads();
        constexpr int NLOAD = (TP % 4 == 0) ? TP : TS_N;
        for (int c = 0; c < CCH; ++c) {
            float bv[NLOAD];
            if constexpr (TP % 4 == 0) {
#pragma unroll
                for (int q = 0; q < TP / 4; ++q)
                    *(float4*)&bv[4 * q] =
                        *(const float4*)&Bls[(c * 64 + lane) * TP + 4 * q];
            } else {
#pragma unroll
                for (int u = 0; u < TS_N; ++u)
                    bv[u] = Bls[(c * 64 + lane) * TP + u];
            }
            float av[TAPS][OCR];
#pragma unroll
            for (int kk = 0; kk < TAPS; ++kk)
#pragma unroll
                for (int j = 0; j < OCR; j += 4)
                    *(float4*)&av[kk][j] =
                        *(const float4*)&Als[(c * TAPS + kk) * OCT + wv * OCR + j];
#pragma unroll
            for (int i = 0; i < OCR; ++i)
#pragma unroll
                for (int t = 0; t < TOUT; ++t)
#pragma unroll
                    for (int kk = 0; kk < TAPS; ++kk)
                        acc[i][t] += av[kk][i] * bv[S * t + D * kk + OFF];
        }
    }
#pragma unroll
    for (int i = 0; i < OCR; ++i)
#pragma unroll
        for (int t = 0; t < TOUT; ++t)
            stc(&Pout[(((size_t)by * 512 + oc0 + wv * OCR + i) * TOUT + t) * 64 +
                      lane],
                acc[i][t]);
}

// ---- red0 body (r16 verbatim + sc1) -------------------------------------
__device__ __forceinline__ void red0_body(int oc, const float* __restrict__ P0,
                                          const float* __restrict__ b1_0,
                                          float* __restrict__ B1, float* Sm) {
    const int tid = threadIdx.x;
    __syncthreads();
    for (int i = tid; i < 768; i += 256) Sm[i] = 0.f;
    __syncthreads();
    if (tid < 176) {
        const int t = tid / 16, b4 = (tid % 16) * 4;
        float4 s = make_float4(0.f, 0.f, 0.f, 0.f);
#pragma unroll
        for (int p = 0; p < 8; ++p)
            s = add4(s, ldc4(P0 + (((size_t)p * 512 + oc) * 11 + t) * 64 + b4));
        s = relu4(addc4(s, b1_0[oc]));
        Sm[(b4 + 0) * 12 + t] = s.x;
        Sm[(b4 + 1) * 12 + t] = s.y;
        Sm[(b4 + 2) * 12 + t] = s.z;
        Sm[(b4 + 3) * 12 + t] = s.w;
    }
    __syncthreads();
    for (int i = tid; i < 192; i += 256)
        stc4(B1 + (size_t)oc * 768 + 4 * i, *(const float4*)&Sm[4 * i]);
}

// ---- red1 body (r16 verbatim + sc1; emits H0f) --------------------------
__device__ __forceinline__ void red1_body(int oc, const float* __restrict__ P1,
                                          const float* __restrict__ b2_0,
                                          const float* __restrict__ PD,
                                          const float* __restrict__ bd0,
                                          float* __restrict__ H0,
                                          float* __restrict__ H0f, float* Sm) {
    const int tid = threadIdx.x;
    __syncthreads();
    for (int i = tid; i < 768; i += 256) Sm[i] = 0.f;
    __syncthreads();
    if (tid < 80) {
        const int t = tid / 16, b4 = (tid % 16) * 4;
        float4 s = make_float4(0.f, 0.f, 0.f, 0.f);
#pragma unroll
        for (int p = 0; p < 16; ++p)
            s = add4(s, ldc4(P1 + (((size_t)p * 512 + oc) * 5 + t) * 64 + b4));
        s = relu4(addc4(s, b2_0[oc]));
        float4 s2 = make_float4(0.f, 0.f, 0.f, 0.f);
#pragma unroll
        for (int p = 0; p < 8; ++p)
            s2 = add4(s2, ldc4(PD + (((size_t)p * 512 + oc) * 5 + t) * 64 + b4));
        s = relu4(addc4(add4(s, s2), bd0[oc]));
        Sm[(b4 + 0) * 12 + t] = s.x;
        Sm[(b4 + 1) * 12 + t] = s.y;
        Sm[(b4 + 2) * 12 + t] = s.z;
        Sm[(b4 + 3) * 12 + t] = s.w;
        if (t == 4) stc4(&H0f[(size_t)oc * 64 + b4], s);
    }
    __syncthreads();
    for (int i = tid; i < 192; i += 256)
        stc4(H0 + (size_t)oc * 768 + 4 * i, *(const float4*)&Sm[4 * i]);
}

// ---- kD body (r16 verbatim + sc1) ---------------------------------------
__device__ __forceinline__ void kD_body(int bid, const float* __restrict__ P2,
                                        const float* __restrict__ b1_1,
                                        const float* __restrict__ w2_1,
                                        float* __restrict__ P3, float* smem) {
  const int tid = threadIdx.x, lane = tid & 63, wv = tid >> 6;
  const int ocp = bid >> 3, ks = bid & 7, oc0 = ocp * 32;
  const int c0 = ks * 64;
  float* Als = smem;         // 6144
  float* Bls = smem + 6144;  // 12288
  float acc[8];
#pragma unroll
  for (int i = 0; i < 8; ++i) acc[i] = 0.f;
  for (int idx = tid; idx < 6144; idx += 256) {
    int i = idx / 192, r = idx % 192, c = r / 3, kk = r % 3;
    Als[(c * 3 + kk) * 32 + i] = w2_1[(oc0 + i) * 1536 + (c0 + c) * 3 + kk];
  }
  for (int idx = tid; idx < 3072; idx += 256) {
    int c = idx / 48, r = idx % 48, u = r / 16, b4 = (r & 15) * 4;
    int cc = c0 + c;
    float4 s = {0.f, 0.f, 0.f, 0.f};
#pragma unroll
    for (int p = 0; p < 8; ++p)
      s = add4(s, ldc4(&P2[((p * 512 + cc) * 3 + u) * 64 + b4]));
    *(float4*)&Bls[(c * 3 + u) * 64 + b4] = relu4(addc4(s, b1_1[cc]));
  }
  __syncthreads();
  for (int c = 0; c < 64; ++c) {
    float bv[3];
#pragma unroll
    for (int u = 0; u < 3; ++u) bv[u] = Bls[(c * 3 + u) * 64 + lane];
    float av[3][8];
#pragma unroll
    for (int kk = 0; kk < 3; ++kk) {
      *(float4*)&av[kk][0] = F4(&Als[(c * 3 + kk) * 32 + wv * 8]);
      *(float4*)&av[kk][4] = F4(&Als[(c * 3 + kk) * 32 + wv * 8 + 4]);
    }
#pragma unroll
    for (int i = 0; i < 8; ++i)
#pragma unroll
      for (int kk = 0; kk < 3; ++kk) acc[i] += av[kk][i] * bv[kk];
  }
#pragma unroll
  for (int i = 0; i < 8; ++i)
    stc(&P3[(ks * 512 + oc0 + wv * 8 + i) * 64 + lane], acc[i]);
}

// ---- kE body (r16 verbatim + sc1 reads) ---------------------------------
__device__ __forceinline__ void kE_body(int j, const float* __restrict__ P3,
                                        const float* __restrict__ b2_1,
                                        const float* __restrict__ H0f,
                                        const float* __restrict__ fcw,
                                        const float* __restrict__ fcb,
                                        float* __restrict__ out, float* smem) {
  const int tid = threadIdx.x, lane = tid & 63, wv = tid >> 6;
  float* H1s = smem;          // 16384
  float* red = smem + 16384;  // 256
  float partial = (wv == 0) ? fcb[j] : 0.f;
  for (int half = 0; half < 2; ++half) {
    const int ocbase = half * 256;
    if (half) __syncthreads();
    for (int idx = tid; idx < 4096; idx += 256) {
      int oc_l = idx >> 4, b4 = (idx & 15) * 4;
      int oc = ocbase + oc_l;
      float4 s = {0.f, 0.f, 0.f, 0.f};
#pragma unroll
      for (int p = 0; p < 8; ++p)
        s = add4(s, ldc4(&P3[(p * 512 + oc) * 64 + b4]));
      s = relu4(addc4(s, b2_1[oc]));
      s = relu4(add4(s, ldc4(&H0f[(size_t)oc * 64 + b4])));
      *(float4*)&H1s[oc_l * 64 + b4] = s;
    }
    __syncthreads();
#pragma unroll 8
    for (int r = 0; r < 64; ++r) {
      int oc_l = wv * 64 + r;
      partial += fcw[j * 512 + ocbase + oc_l] * H1s[oc_l * 64 + lane];
    }
  }
  red[wv * 64 + lane] = partial;
  __syncthreads();
  if (wv == 0)
    out[lane * OUTD + j] = red[0 * 64 + lane] + red[1 * 64 + lane] +
                           red[2 * 64 + lane] + red[3 * 64 + lane];
}

struct Params {
  const float* x;
  const float *w1_0, *b1_0, *w2_0, *b2_0, *wd0, *bd0;
  const float *w1_1, *b1_1, *w2_1, *b2_1, *fcw, *fcb;
  float* out;
  float *P0, *B1, *P1, *PD, *H0, *P2, *P3, *H0f;
  int* FL;
};

__global__ __launch_bounds__(256, 2) void mega(Params p) {
  __shared__ float smem[18688];  // 74.75 KB
  const int bid = blockIdx.x;

  // Phase 1: L0 conv (all 256: 32 ocp x 8 ks), then down conv (bid<128)
  conv_body<256, 13, 13, 11, 1, 1, 0, 3, 16, 16, 2, true, 0, 1>(
      bid >> 3, bid & 7, p.x, p.w1_0, p.P0, smem);
  if (bid < 128) {
    __syncthreads();  // guard LDS reuse
    conv_body<256, 5, 5, 5, 1, 0, 0, 1, 32, 16, 2, true, 4, 2>(
        bid >> 3, bid & 7, p.x, p.wd0, p.PD, smem);
  }
  gbar(&p.FL[0]);

  // Phase 2: red0 — B1 = relu(sum8 P0 + b1_0); oc = bid, bid+256
  red0_body(bid, p.P0, p.b1_0, p.B1, smem);
  red0_body(bid + 256, p.P0, p.b1_0, p.B1, smem);
  gbar(&p.FL[1]);

  // Phase 3: convL1 — B1 -> P1 (16 ocp x 16 ks)
  conv_body<512, 11, 12, 5, 2, 1, 0, 3, 32, 16, 2, false, 0, 0>(
      bid & 15, bid >> 4, p.B1, p.w2_0, p.P1, smem);
  gbar(&p.FL[2]);

  // Phase 4: red1 — H0 (+H0f); oc = bid, bid+256
  red1_body(bid, p.P1, p.b2_0, p.PD, p.bd0, p.H0, p.H0f, smem);
  red1_body(bid + 256, p.P1, p.b2_0, p.PD, p.bd0, p.H0, p.H0f, smem);
  gbar(&p.FL[3]);

  // Phase 5: convL2 — H0 -> P2 (16 ocp x 8 ks; bid < 128)
  if (bid < 128)
    conv_body<512, 5, 12, 3, 1, 1, 0, 3, 32, 16, 4, false, 0, 0>(
        bid & 15, bid >> 4, p.H0, p.w1_1, p.P2, smem);
  gbar(&p.FL[4]);

  // Phase 6: kD — stage B2 = relu(sum8 P2 + b1_1); L3 conv -> P3 (bid<128)
  if (bid < 128) kD_body(bid, p.P2, p.b1_1, p.w2_1, p.P3, smem);
  gbar(&p.FL[5]);

  // Phase 7: kE — fc with fused sum8 P3 + residual (bid < 36)
  if (bid < 36)
    kE_body(bid, p.P3, p.b2_1, p.H0f, p.fcw, p.fcb, p.out, smem);
}

extern "C" void kernel_launch(void* const* d_in, const int* in_sizes, int n_in,
                              void* d_out, int out_size, void* d_ws, size_t ws_size,
                              hipStream_t stream) {
  Params p;
  p.x    = (const float*)d_in[0];
  p.w1_0 = (const float*)d_in[4];
  p.b1_0 = (const float*)d_in[5];
  p.w2_0 = (const float*)d_in[6];
  p.b2_0 = (const float*)d_in[7];
  p.wd0  = (const float*)d_in[8];
  p.bd0  = (const float*)d_in[9];
  p.w1_1 = (const float*)d_in[10];
  p.b1_1 = (const float*)d_in[11];
  p.w2_1 = (const float*)d_in[12];
  p.b2_1 = (const float*)d_in[13];
  p.fcw  = (const float*)d_in[14];
  p.fcb  = (const float*)d_in[15];
  p.out  = (float*)d_out;

  float* base = (float*)d_ws;    // layout identical to rounds 15/16
  p.P0  = base;                  // 8*512*11*64 = 2,883,584
  p.B1  = p.P0 + 2883584;        // 512*64*12   =   393,216
  p.P1  = p.B1 + 393216;         // 16*512*5*64 = 2,621,440
  p.PD  = p.P1 + 2621440;        // 8*512*5*64  = 1,310,720
  p.H0  = p.PD + 1310720;        // 512*64*12   =   393,216
  p.P2  = p.H0 + 393216;         // 8*512*3*64  =   786,432
  p.P3  = p.P2 + 786432;         // 8*512*64    =   262,144
  p.H0f = p.P3 + 262144;         // 512*64      =    32,768
  p.FL  = (int*)(p.H0f + 32768); // 6 ints

  hipMemsetAsync((void*)p.FL, 0, 6 * sizeof(int), stream);
  mega<<<NB, 256, 0, stream>>>(p);
}